// Round 2
// 297.415 us; speedup vs baseline: 1.0066x; 1.0066x over previous
//
#include <hip/hip_runtime.h>

// Word embedding gather: out[t, :] = weight[ids[t], :]
// weight: [50257, 1024] fp32, ids: [16*2048] int32, out: [32768, 1024] fp32.
//
// v2b: latency-bound fix. One block per 8 tokens (was 1). Preload all 8 ids
// (wave-uniform -> scalar loads), then issue 8 independent float4 row-loads
// before any store -> 8x memory-level parallelism per wave. Non-temporal
// stores keep the 134 MB output stream from evicting weight rows in L2/L3.
// Uses native ext_vector_type float4 (HIP's float4 class is rejected by
// __builtin_nontemporal_store).

#define DIM 1024
#define TPB 8  // tokens per block

typedef float f32x4 __attribute__((ext_vector_type(4)));

__global__ __launch_bounds__(256) void WordEmbedding_kernel(
    const float* __restrict__ weight,
    const int* __restrict__ ids,
    float* __restrict__ out) {
    const int t0 = blockIdx.x * TPB;
    const int tid = threadIdx.x;  // 0..255, one float4 lane-slot across the row

    // Preload ids for all tokens this block handles (uniform -> s_load).
    int idx[TPB];
#pragma unroll
    for (int k = 0; k < TPB; ++k) {
        idx[k] = ids[t0 + k];
    }

    // Issue all row loads back-to-back: 8 outstanding global_load_dwordx4
    // per wave before the first s_waitcnt.
    f32x4 v[TPB];
#pragma unroll
    for (int k = 0; k < TPB; ++k) {
        const f32x4* __restrict__ src =
            (const f32x4*)(weight + (size_t)idx[k] * DIM);
        v[k] = src[tid];
    }

    // Streaming stores (no reuse of out) -> don't pollute L2/L3.
#pragma unroll
    for (int k = 0; k < TPB; ++k) {
        f32x4* dst = (f32x4*)(out + (size_t)(t0 + k) * DIM);
        __builtin_nontemporal_store(v[k], dst + tid);
    }
}

extern "C" void kernel_launch(void* const* d_in, const int* in_sizes, int n_in,
                              void* d_out, int out_size, void* d_ws, size_t ws_size,
                              hipStream_t stream) {
    const float* weight = (const float*)d_in[0];
    const int* ids = (const int*)d_in[1];
    float* out = (float*)d_out;
    const int n_tokens = in_sizes[1];  // 16 * 2048 = 32768
    const int n_blocks = n_tokens / TPB;  // 4096 (exact)
    WordEmbedding_kernel<<<n_blocks, DIM / 4, 0, stream>>>(weight, ids, out);
}